// Round 6
// baseline (110.100 us; speedup 1.0000x reference)
//
#include <hip/hip_runtime.h>

#define SEQ_LEN   512
#define PRED_LEN  96
#define PATCH_LEN 16
#define STRIDE    8
#define NQ        4
#define NUM_PATCHES 63
#define BB        32
#define MM        128
#define NROWS     (BB*MM)            // 4096
#define FAN_IN    (NUM_PATCHES*NQ)   // 252

// ---------------- kernel 0: build the full 16x16 circuit unitary ----------------
// Output layout (column-major): u[k*32 + i] = Re U[i][k], u[k*32+16+i] = Im U[i][k]
__global__ __launch_bounds__(128) void build_u_kernel(const float* __restrict__ w,
                                                      float* __restrict__ u) {
    __shared__ float Ur[16][17], Ui[16][17];
    const int tid = threadIdx.x;
    const int col = tid & 15;
    const int pr  = tid >> 4;        // pair index 0..7

    for (int idx = tid; idx < 256; idx += 128) {
        int i = idx >> 4, j = idx & 15;
        Ur[i][j] = (i == j) ? 1.f : 0.f;
        Ui[i][j] = 0.f;
    }

    for (int l = 0; l < 3; ++l) {
        for (int wi = 0; wi < 4; ++wi) {
            const float* g = w + (l*4 + wi)*3;
            float phi = g[0], th = g[1], om = g[2];
            float ct = cosf(0.5f*th), st = sinf(0.5f*th);
            float ap = 0.5f*(phi+om), am = 0.5f*(phi-om);
            float m00r =  cosf(ap)*ct, m00i = -sinf(ap)*ct;
            float m01r = -cosf(am)*st, m01i = -sinf(am)*st;
            float m10r =  cosf(am)*st, m10i = -sinf(am)*st;
            float m11r =  cosf(ap)*ct, m11i =  sinf(ap)*ct;
            int bp = 3 - wi;                                  // wire wi <-> bit 3-wi
            int i0 = ((pr >> bp) << (bp+1)) | (pr & ((1<<bp)-1));
            int i1 = i0 | (1 << bp);
            __syncthreads();
            float a_r = Ur[i0][col], a_i = Ui[i0][col];
            float b_r = Ur[i1][col], b_i = Ui[i1][col];
            Ur[i0][col] = m00r*a_r - m00i*a_i + m01r*b_r - m01i*b_i;
            Ui[i0][col] = m00r*a_i + m00i*a_r + m01r*b_i + m01i*b_r;
            Ur[i1][col] = m10r*a_r - m10i*a_i + m11r*b_r - m11i*b_i;
            Ui[i1][col] = m10r*a_i + m10i*a_r + m11r*b_i + m11i*b_r;
        }
        int r = (l % 3) + 1;                                  // ranges: 1,2,3
        for (int wi = 0; wi < 4; ++wi) {
            int cm = 8 >> wi, tm = 8 >> ((wi + r) & 3);
            __syncthreads();
            if (pr < 4) {
                int i = cm, prr = pr;
                int rem = 15 & ~cm & ~tm;
                for (int bpos = 0; bpos < 4; ++bpos)
                    if (rem & (1 << bpos)) { if (prr & 1) i |= (1 << bpos); prr >>= 1; }
                int j = i | tm;
                float tr = Ur[i][col], ti = Ui[i][col];
                Ur[i][col] = Ur[j][col]; Ui[i][col] = Ui[j][col];
                Ur[j][col] = tr;         Ui[j][col] = ti;
            }
        }
    }
    __syncthreads();
    for (int idx = tid; idx < 256; idx += 128) {
        int k = idx >> 4, i = idx & 15;
        u[k*32 + i]      = Ur[i][k];
        u[k*32 + 16 + i] = Ui[i][k];
    }
}

// ---------------- kernel 1: encode = U matvec + PauliZ ----------------
// 1D grid 1008 = 63 p x 16 yq, XCD-chunked: XCD k handles b in [4k, 4k+4)
__global__ __launch_bounds__(256) void encode_kernel(const float* __restrict__ x,
                                                     const float* __restrict__ u,
                                                     float* __restrict__ enc_t) {
    const int L   = blockIdx.x;            // 0..1007
    const int xcd = L & 7;
    const int idx = L >> 3;                // 0..125
    const int p   = idx % 63;
    const int yq  = xcd * 2 + idx / 63;    // 0..15
    const int row = yq * 256 + threadIdx.x;
    const int b   = row >> 7;
    const int m   = row & 127;
    const float* xp = x + b * (SEQ_LEN * MM) + p * STRIDE * MM + m;

    float v[16];
    float tot = 0.f;
    #pragma unroll
    for (int k = 0; k < 16; ++k) {
        v[k] = xp[k * MM] + 1e-6f;
        tot = fmaf(v[k], v[k], tot);        // ||v||^2 (= ||Uv||^2, U unitary)
    }
    float yr[16], yi[16];
    #pragma unroll
    for (int i = 0; i < 16; ++i) { yr[i] = 0.f; yi[i] = 0.f; }
    #pragma unroll
    for (int k = 0; k < 16; ++k) {
        const float* uc = u + k * 32;       // uniform -> s_load
        #pragma unroll
        for (int i = 0; i < 16; ++i) {
            yr[i] = fmaf(uc[i],      v[k], yr[i]);
            yi[i] = fmaf(uc[16 + i], v[k], yi[i]);
        }
    }
    float z0 = 0.f, z1 = 0.f, z2 = 0.f, z3 = 0.f;
    #pragma unroll
    for (int i = 0; i < 16; ++i) {
        float pr2 = yr[i]*yr[i] + yi[i]*yi[i];
        z0 += (i & 8) ? -pr2 : pr2;
        z1 += (i & 4) ? -pr2 : pr2;
        z2 += (i & 2) ? -pr2 : pr2;
        z3 += (i & 1) ? -pr2 : pr2;
    }
    const float invt = 1.0f / tot;
    float* e = enc_t + p * 4 * NROWS + row;
    e[0*NROWS] = z0 * invt;
    e[1*NROWS] = z1 * invt;
    e[2*NROWS] = z2 * invt;
    e[3*NROWS] = z3 * invt;
}

// ---------------- kernel 2: fused head + skip GEMM ----------------
// block = 256: 64 row-lanes x 4 K-split waves; weights via wave-uniform float4
// (s_load_dwordx4). Swizzle: XCD-chunked on b, TILE SLOWEST within an XCD chunk
// so co-resident blocks on a CU share one tile's 18 KB weight set (K$-friendly).
#define TT 6
__global__ __launch_bounds__(256) void head_kernel(const float* __restrict__ x,
                                                   const float* __restrict__ enc_t,
                                                   const float* __restrict__ head_w,
                                                   const float* __restrict__ head_b,
                                                   const float* __restrict__ skip_w,
                                                   const float* __restrict__ skip_b,
                                                   float* __restrict__ out) {
    const int tid  = threadIdx.x;
    const int lane = tid & 63;
    const int ks   = __builtin_amdgcn_readfirstlane(tid >> 6);  // wave id 0..3

    // bijective swizzle: xcd = L&7; within chunk, tile is SLOW, (b_local,mh) fast
    const int L    = blockIdx.x;              // 0..1023
    const int xcd  = L & 7;
    const int c    = L >> 3;                  // 0..127
    const int tile = c >> 3;                  // 0..15  (slow)
    const int pos  = c & 7;                   // 0..7   (fast)
    const int b    = xcd * 4 + (pos >> 1);    // 0..31  (matches encode's b->XCD map)
    const int mh   = pos & 1;
    const int t0   = tile * TT;
    const int row  = b * MM + mh * 64 + lane;

    float acc[TT];
    #pragma unroll
    for (int tt = 0; tt < TT; ++tt) acc[tt] = 0.f;

    // enc part: 63 4-k chunks split 16/16/16/15 across waves; A-loads 16-deep
    {
        const float* e = enc_t + row;
        #pragma unroll 1
        for (int gb = 0; gb < 4; ++gb) {
            float a[16];
            #pragma unroll
            for (int i = 0; i < 16; ++i) {
                const int j = (ks * 16 + gb * 4) * 4 + i;
                a[i] = (j < FAN_IN) ? e[j * NROWS] : 0.f;
            }
            #pragma unroll
            for (int cb = 0; cb < 4; ++cb) {
                const int ch = ks * 16 + gb * 4 + cb;
                if (ch < 63) {
                    const int j0 = ch * 4;
                    #pragma unroll
                    for (int tt = 0; tt < TT; ++tt) {
                        const float4 wv = *(const float4*)(head_w + (t0+tt)*FAN_IN + j0);
                        acc[tt] = fmaf(a[cb*4+0], wv.x, acc[tt]);
                        acc[tt] = fmaf(a[cb*4+1], wv.y, acc[tt]);
                        acc[tt] = fmaf(a[cb*4+2], wv.z, acc[tt]);
                        acc[tt] = fmaf(a[cb*4+3], wv.w, acc[tt]);
                    }
                }
            }
        }
    }
    // skip part: 128 4-k chunks, 32 per wave; A-loads 16-deep
    {
        const float* xr = x + b * (SEQ_LEN * MM) + mh * 64 + lane;
        #pragma unroll 1
        for (int gb = 0; gb < 8; ++gb) {
            float a[16];
            const int l0g = (ks * 32 + gb * 4) * 4;
            #pragma unroll
            for (int i = 0; i < 16; ++i) a[i] = xr[(l0g + i) * MM];
            #pragma unroll
            for (int cb = 0; cb < 4; ++cb) {
                const int l0 = l0g + cb * 4;
                #pragma unroll
                for (int tt = 0; tt < TT; ++tt) {
                    const float4 wv = *(const float4*)(skip_w + (t0+tt)*SEQ_LEN + l0);
                    acc[tt] = fmaf(a[cb*4+0], wv.x, acc[tt]);
                    acc[tt] = fmaf(a[cb*4+1], wv.y, acc[tt]);
                    acc[tt] = fmaf(a[cb*4+2], wv.z, acc[tt]);
                    acc[tt] = fmaf(a[cb*4+3], wv.w, acc[tt]);
                }
            }
        }
    }

    __shared__ float red[TT][256];
    #pragma unroll
    for (int tt = 0; tt < TT; ++tt) red[tt][tid] = acc[tt];
    __syncthreads();

    if (tid < 64) {
        float* o = out + b * (PRED_LEN * MM) + t0 * MM + mh * 64 + lane;
        #pragma unroll
        for (int tt = 0; tt < TT; ++tt) {
            float s = red[tt][lane] + red[tt][lane+64] + red[tt][lane+128] + red[tt][lane+192];
            o[tt * MM] = s + head_b[t0+tt] + skip_b[t0+tt];
        }
    }
}

extern "C" void kernel_launch(void* const* d_in, const int* in_sizes, int n_in,
                              void* d_out, int out_size, void* d_ws, size_t ws_size,
                              hipStream_t stream) {
    const float* x       = (const float*)d_in[0];
    const float* weights = (const float*)d_in[1];
    const float* head_w  = (const float*)d_in[2];
    const float* head_b  = (const float*)d_in[3];
    const float* skip_w  = (const float*)d_in[4];
    const float* skip_b  = (const float*)d_in[5];
    float* out = (float*)d_out;

    float* u     = (float*)d_ws;              // 512 floats
    float* enc_t = (float*)d_ws + 1024;       // 252*4096 floats = 4.13 MB

    hipLaunchKernelGGL(build_u_kernel, dim3(1), dim3(128), 0, stream, weights, u);
    hipLaunchKernelGGL(encode_kernel, dim3(63*16), dim3(256), 0, stream,
                       x, u, enc_t);
    hipLaunchKernelGGL(head_kernel, dim3(1024), dim3(256), 0, stream,
                       x, enc_t, head_w, head_b, skip_w, skip_b, out);
}

// Round 7
// 107.557 us; speedup vs baseline: 1.0236x; 1.0236x over previous
//
#include <hip/hip_runtime.h>

#define SEQ_LEN   512
#define PRED_LEN  96
#define PATCH_LEN 16
#define STRIDE    8
#define NQ        4
#define NUM_PATCHES 63
#define BB        32
#define MM        128
#define NROWS     (BB*MM)            // 4096
#define FAN_IN    (NUM_PATCHES*NQ)   // 252

// ---------------- kernel 0: build the full 16x16 circuit unitary ----------------
// Output layout (column-major): u[k*32 + i] = Re U[i][k], u[k*32+16+i] = Im U[i][k]
__global__ __launch_bounds__(128) void build_u_kernel(const float* __restrict__ w,
                                                      float* __restrict__ u) {
    __shared__ float Ur[16][17], Ui[16][17];
    const int tid = threadIdx.x;
    const int col = tid & 15;
    const int pr  = tid >> 4;        // pair index 0..7

    for (int idx = tid; idx < 256; idx += 128) {
        int i = idx >> 4, j = idx & 15;
        Ur[i][j] = (i == j) ? 1.f : 0.f;
        Ui[i][j] = 0.f;
    }

    for (int l = 0; l < 3; ++l) {
        for (int wi = 0; wi < 4; ++wi) {
            const float* g = w + (l*4 + wi)*3;
            float phi = g[0], th = g[1], om = g[2];
            float ct = cosf(0.5f*th), st = sinf(0.5f*th);
            float ap = 0.5f*(phi+om), am = 0.5f*(phi-om);
            float m00r =  cosf(ap)*ct, m00i = -sinf(ap)*ct;
            float m01r = -cosf(am)*st, m01i = -sinf(am)*st;
            float m10r =  cosf(am)*st, m10i = -sinf(am)*st;
            float m11r =  cosf(ap)*ct, m11i =  sinf(ap)*ct;
            int bp = 3 - wi;                                  // wire wi <-> bit 3-wi
            int i0 = ((pr >> bp) << (bp+1)) | (pr & ((1<<bp)-1));
            int i1 = i0 | (1 << bp);
            __syncthreads();
            float a_r = Ur[i0][col], a_i = Ui[i0][col];
            float b_r = Ur[i1][col], b_i = Ui[i1][col];
            Ur[i0][col] = m00r*a_r - m00i*a_i + m01r*b_r - m01i*b_i;
            Ui[i0][col] = m00r*a_i + m00i*a_r + m01r*b_i + m01i*b_r;
            Ur[i1][col] = m10r*a_r - m10i*a_i + m11r*b_r - m11i*b_i;
            Ui[i1][col] = m10r*a_i + m10i*a_r + m11r*b_i + m11i*b_r;
        }
        int r = (l % 3) + 1;                                  // ranges: 1,2,3
        for (int wi = 0; wi < 4; ++wi) {
            int cm = 8 >> wi, tm = 8 >> ((wi + r) & 3);
            __syncthreads();
            if (pr < 4) {
                int i = cm, prr = pr;
                int rem = 15 & ~cm & ~tm;
                for (int bpos = 0; bpos < 4; ++bpos)
                    if (rem & (1 << bpos)) { if (prr & 1) i |= (1 << bpos); prr >>= 1; }
                int j = i | tm;
                float tr = Ur[i][col], ti = Ui[i][col];
                Ur[i][col] = Ur[j][col]; Ui[i][col] = Ui[j][col];
                Ur[j][col] = tr;         Ui[j][col] = ti;
            }
        }
    }
    __syncthreads();
    for (int idx = tid; idx < 256; idx += 128) {
        int k = idx >> 4, i = idx & 15;
        u[k*32 + i]      = Ur[i][k];
        u[k*32 + 16 + i] = Ui[i][k];
    }
}

// ---------------- kernel 1: encode = U matvec + PauliZ ----------------
// 1D grid 1008 = 63 p x 16 yq, XCD-chunked: XCD k handles b in [4k, 4k+4)
__global__ __launch_bounds__(256) void encode_kernel(const float* __restrict__ x,
                                                     const float* __restrict__ u,
                                                     float* __restrict__ enc_t) {
    const int L   = blockIdx.x;            // 0..1007
    const int xcd = L & 7;
    const int idx = L >> 3;                // 0..125
    const int p   = idx % 63;
    const int yq  = xcd * 2 + idx / 63;    // 0..15
    const int row = yq * 256 + threadIdx.x;
    const int b   = row >> 7;
    const int m   = row & 127;
    const float* xp = x + b * (SEQ_LEN * MM) + p * STRIDE * MM + m;

    float v[16];
    float tot = 0.f;
    #pragma unroll
    for (int k = 0; k < 16; ++k) {
        v[k] = xp[k * MM] + 1e-6f;
        tot = fmaf(v[k], v[k], tot);        // ||v||^2 (= ||Uv||^2, U unitary)
    }
    float yr[16], yi[16];
    #pragma unroll
    for (int i = 0; i < 16; ++i) { yr[i] = 0.f; yi[i] = 0.f; }
    #pragma unroll
    for (int k = 0; k < 16; ++k) {
        const float* uc = u + k * 32;       // uniform -> s_load
        #pragma unroll
        for (int i = 0; i < 16; ++i) {
            yr[i] = fmaf(uc[i],      v[k], yr[i]);
            yi[i] = fmaf(uc[16 + i], v[k], yi[i]);
        }
    }
    float z0 = 0.f, z1 = 0.f, z2 = 0.f, z3 = 0.f;
    #pragma unroll
    for (int i = 0; i < 16; ++i) {
        float pr2 = yr[i]*yr[i] + yi[i]*yi[i];
        z0 += (i & 8) ? -pr2 : pr2;
        z1 += (i & 4) ? -pr2 : pr2;
        z2 += (i & 2) ? -pr2 : pr2;
        z3 += (i & 1) ? -pr2 : pr2;
    }
    const float invt = 1.0f / tot;
    float* e = enc_t + p * 4 * NROWS + row;
    e[0*NROWS] = z0 * invt;
    e[1*NROWS] = z1 * invt;
    e[2*NROWS] = z2 * invt;
    e[3*NROWS] = z3 * invt;
}

// ---------------- kernel 2: fused head + skip GEMM ----------------
// block = 512: 64 row-lanes x 8 K-split waves; weights via wave-uniform float4
// (s_load_dwordx4). TT=12 halves A-side L2 traffic vs TT=6 (each A value
// re-read 96/TT times). Swizzle: tile FASTEST so co-resident blocks share
// the same (b,mh) A-rows in L1/L2 (R5 ordering, proven best).
#define TT 12
__global__ __launch_bounds__(512) void head_kernel(const float* __restrict__ x,
                                                   const float* __restrict__ enc_t,
                                                   const float* __restrict__ head_w,
                                                   const float* __restrict__ head_b,
                                                   const float* __restrict__ skip_w,
                                                   const float* __restrict__ skip_b,
                                                   float* __restrict__ out) {
    const int tid  = threadIdx.x;
    const int lane = tid & 63;
    const int ks   = __builtin_amdgcn_readfirstlane(tid >> 6);  // wave id 0..7

    // bijective swizzle: xcd = L&7; within chunk tile is FASTEST, (b_local,mh) slow
    const int L    = blockIdx.x;              // 0..511
    const int xcd  = L & 7;
    const int c    = L >> 3;                  // 0..63
    const int tile = c & 7;                   // 0..7   (fast)
    const int pos  = c >> 3;                  // 0..7   (slow)
    const int b    = xcd * 4 + (pos >> 1);    // matches encode's b->XCD map
    const int mh   = pos & 1;
    const int t0   = tile * TT;
    const int row  = b * MM + mh * 64 + lane;

    float acc[TT];
    #pragma unroll
    for (int tt = 0; tt < TT; ++tt) acc[tt] = 0.f;

    // enc part: 63 4-k quads split 8/wave (wave 7 gets 7)
    {
        const float* e = enc_t + row;
        #pragma unroll 4
        for (int cb = 0; cb < 8; ++cb) {
            const int ch = ks * 8 + cb;
            if (ch < 63) {
                const int j0 = ch * 4;
                float a0 = e[(j0+0)*NROWS], a1 = e[(j0+1)*NROWS];
                float a2 = e[(j0+2)*NROWS], a3 = e[(j0+3)*NROWS];
                #pragma unroll
                for (int tt = 0; tt < TT; ++tt) {
                    const float4 wv = *(const float4*)(head_w + (t0+tt)*FAN_IN + j0);
                    acc[tt] = fmaf(a0, wv.x, acc[tt]);
                    acc[tt] = fmaf(a1, wv.y, acc[tt]);
                    acc[tt] = fmaf(a2, wv.z, acc[tt]);
                    acc[tt] = fmaf(a3, wv.w, acc[tt]);
                }
            }
        }
    }
    // skip part: 128 4-k quads, 16 per wave
    {
        const float* xr = x + b * (SEQ_LEN * MM) + mh * 64 + lane;
        #pragma unroll 4
        for (int cb = 0; cb < 16; ++cb) {
            const int l0 = (ks * 16 + cb) * 4;
            float a0 = xr[(l0+0)*MM], a1 = xr[(l0+1)*MM];
            float a2 = xr[(l0+2)*MM], a3 = xr[(l0+3)*MM];
            #pragma unroll
            for (int tt = 0; tt < TT; ++tt) {
                const float4 wv = *(const float4*)(skip_w + (t0+tt)*SEQ_LEN + l0);
                acc[tt] = fmaf(a0, wv.x, acc[tt]);
                acc[tt] = fmaf(a1, wv.y, acc[tt]);
                acc[tt] = fmaf(a2, wv.z, acc[tt]);
                acc[tt] = fmaf(a3, wv.w, acc[tt]);
            }
        }
    }

    __shared__ float red[TT][512];
    #pragma unroll
    for (int tt = 0; tt < TT; ++tt) red[tt][tid] = acc[tt];
    __syncthreads();

    if (tid < 64) {
        float* o = out + b * (PRED_LEN * MM) + t0 * MM + mh * 64 + lane;
        #pragma unroll
        for (int tt = 0; tt < TT; ++tt) {
            float s = 0.f;
            #pragma unroll
            for (int w = 0; w < 8; ++w) s += red[tt][lane + w*64];
            o[tt * MM] = s + head_b[t0+tt] + skip_b[t0+tt];
        }
    }
}

extern "C" void kernel_launch(void* const* d_in, const int* in_sizes, int n_in,
                              void* d_out, int out_size, void* d_ws, size_t ws_size,
                              hipStream_t stream) {
    const float* x       = (const float*)d_in[0];
    const float* weights = (const float*)d_in[1];
    const float* head_w  = (const float*)d_in[2];
    const float* head_b  = (const float*)d_in[3];
    const float* skip_w  = (const float*)d_in[4];
    const float* skip_b  = (const float*)d_in[5];
    float* out = (float*)d_out;

    float* u     = (float*)d_ws;              // 512 floats
    float* enc_t = (float*)d_ws + 1024;       // 252*4096 floats = 4.13 MB

    hipLaunchKernelGGL(build_u_kernel, dim3(1), dim3(128), 0, stream, weights, u);
    hipLaunchKernelGGL(encode_kernel, dim3(63*16), dim3(256), 0, stream,
                       x, u, enc_t);
    hipLaunchKernelGGL(head_kernel, dim3(512), dim3(512), 0, stream,
                       x, enc_t, head_w, head_b, skip_w, skip_b, out);
}

// Round 8
// 104.073 us; speedup vs baseline: 1.0579x; 1.0335x over previous
//
#include <hip/hip_runtime.h>

#define SEQ_LEN   512
#define PRED_LEN  96
#define PATCH_LEN 16
#define STRIDE    8
#define NQ        4
#define NUM_PATCHES 63
#define BB        32
#define MM        128
#define NROWS     (BB*MM)            // 4096
#define FAN_IN    (NUM_PATCHES*NQ)   // 252

// ---------------- kernel 0: build the full 16x16 circuit unitary ----------------
// Output layout (column-major): u[k*32 + i] = Re U[i][k], u[k*32+16+i] = Im U[i][k]
__global__ __launch_bounds__(128) void build_u_kernel(const float* __restrict__ w,
                                                      float* __restrict__ u) {
    __shared__ float Ur[16][17], Ui[16][17];
    const int tid = threadIdx.x;
    const int col = tid & 15;
    const int pr  = tid >> 4;        // pair index 0..7

    for (int idx = tid; idx < 256; idx += 128) {
        int i = idx >> 4, j = idx & 15;
        Ur[i][j] = (i == j) ? 1.f : 0.f;
        Ui[i][j] = 0.f;
    }

    for (int l = 0; l < 3; ++l) {
        for (int wi = 0; wi < 4; ++wi) {
            const float* g = w + (l*4 + wi)*3;
            float phi = g[0], th = g[1], om = g[2];
            float ct = cosf(0.5f*th), st = sinf(0.5f*th);
            float ap = 0.5f*(phi+om), am = 0.5f*(phi-om);
            float m00r =  cosf(ap)*ct, m00i = -sinf(ap)*ct;
            float m01r = -cosf(am)*st, m01i = -sinf(am)*st;
            float m10r =  cosf(am)*st, m10i = -sinf(am)*st;
            float m11r =  cosf(ap)*ct, m11i =  sinf(ap)*ct;
            int bp = 3 - wi;                                  // wire wi <-> bit 3-wi
            int i0 = ((pr >> bp) << (bp+1)) | (pr & ((1<<bp)-1));
            int i1 = i0 | (1 << bp);
            __syncthreads();
            float a_r = Ur[i0][col], a_i = Ui[i0][col];
            float b_r = Ur[i1][col], b_i = Ui[i1][col];
            Ur[i0][col] = m00r*a_r - m00i*a_i + m01r*b_r - m01i*b_i;
            Ui[i0][col] = m00r*a_i + m00i*a_r + m01r*b_i + m01i*b_r;
            Ur[i1][col] = m10r*a_r - m10i*a_i + m11r*b_r - m11i*b_i;
            Ui[i1][col] = m10r*a_i + m10i*a_r + m11r*b_i + m11i*b_r;
        }
        int r = (l % 3) + 1;                                  // ranges: 1,2,3
        for (int wi = 0; wi < 4; ++wi) {
            int cm = 8 >> wi, tm = 8 >> ((wi + r) & 3);
            __syncthreads();
            if (pr < 4) {
                int i = cm, prr = pr;
                int rem = 15 & ~cm & ~tm;
                for (int bpos = 0; bpos < 4; ++bpos)
                    if (rem & (1 << bpos)) { if (prr & 1) i |= (1 << bpos); prr >>= 1; }
                int j = i | tm;
                float tr = Ur[i][col], ti = Ui[i][col];
                Ur[i][col] = Ur[j][col]; Ui[i][col] = Ui[j][col];
                Ur[j][col] = tr;         Ui[j][col] = ti;
            }
        }
    }
    __syncthreads();
    for (int idx = tid; idx < 256; idx += 128) {
        int k = idx >> 4, i = idx & 15;
        u[k*32 + i]      = Ur[i][k];
        u[k*32 + 16 + i] = Ui[i][k];
    }
}

// ---------------- kernel 1: encode = U matvec + PauliZ ----------------
// 1D grid 1008 = 63 p x 16 yq, XCD-chunked: XCD k handles b in [4k, 4k+4)
__global__ __launch_bounds__(256) void encode_kernel(const float* __restrict__ x,
                                                     const float* __restrict__ u,
                                                     float* __restrict__ enc_t) {
    const int L   = blockIdx.x;            // 0..1007
    const int xcd = L & 7;
    const int idx = L >> 3;                // 0..125
    const int p   = idx % 63;
    const int yq  = xcd * 2 + idx / 63;    // 0..15
    const int row = yq * 256 + threadIdx.x;
    const int b   = row >> 7;
    const int m   = row & 127;
    const float* xp = x + b * (SEQ_LEN * MM) + p * STRIDE * MM + m;

    float v[16];
    float tot = 0.f;
    #pragma unroll
    for (int k = 0; k < 16; ++k) {
        v[k] = xp[k * MM] + 1e-6f;
        tot = fmaf(v[k], v[k], tot);        // ||v||^2 (= ||Uv||^2, U unitary)
    }
    float yr[16], yi[16];
    #pragma unroll
    for (int i = 0; i < 16; ++i) { yr[i] = 0.f; yi[i] = 0.f; }
    #pragma unroll
    for (int k = 0; k < 16; ++k) {
        const float* uc = u + k * 32;       // uniform -> s_load
        #pragma unroll
        for (int i = 0; i < 16; ++i) {
            yr[i] = fmaf(uc[i],      v[k], yr[i]);
            yi[i] = fmaf(uc[16 + i], v[k], yi[i]);
        }
    }
    float z0 = 0.f, z1 = 0.f, z2 = 0.f, z3 = 0.f;
    #pragma unroll
    for (int i = 0; i < 16; ++i) {
        float pr2 = yr[i]*yr[i] + yi[i]*yi[i];
        z0 += (i & 8) ? -pr2 : pr2;
        z1 += (i & 4) ? -pr2 : pr2;
        z2 += (i & 2) ? -pr2 : pr2;
        z3 += (i & 1) ? -pr2 : pr2;
    }
    const float invt = 1.0f / tot;
    float* e = enc_t + p * 4 * NROWS + row;
    e[0*NROWS] = z0 * invt;
    e[1*NROWS] = z1 * invt;
    e[2*NROWS] = z2 * invt;
    e[3*NROWS] = z3 * invt;
}

// ---------------- kernel 2: fused head + skip GEMM ----------------
// R4-best structure (105.3 us): block 256 = 64 lanes x 4 K-split waves,
// grid 1024 = 32 b x 2 mh x 16 tiles (TT=6), tile FASTEST in swizzle,
// wave-uniform float4 weight loads (s_load_dwordx4).
// NEW: 2-stage software pipeline — next quad's A-loads issue before this
// quad's FMA block, overlapping VMEM/SMEM latency with the 48 FMA cycles.
#define TT 6
__global__ __launch_bounds__(256) void head_kernel(const float* __restrict__ x,
                                                   const float* __restrict__ enc_t,
                                                   const float* __restrict__ head_w,
                                                   const float* __restrict__ head_b,
                                                   const float* __restrict__ skip_w,
                                                   const float* __restrict__ skip_b,
                                                   float* __restrict__ out) {
    const int tid  = threadIdx.x;
    const int lane = tid & 63;
    const int ks   = __builtin_amdgcn_readfirstlane(tid >> 6);  // wave id 0..3

    // bijective XCD-chunk swizzle, tile fastest (R4-best)
    const int L = blockIdx.x;                 // 0..1023
    const int T = (L & 7) * 128 + (L >> 3);
    const int b    = T >> 5;                  // 0..31
    const int mh   = (T >> 4) & 1;            // 0..1
    const int tile = T & 15;                  // 0..15
    const int t0   = tile * TT;
    const int row  = b * MM + mh * 64 + lane;

    float acc[TT];
    #pragma unroll
    for (int tt = 0; tt < TT; ++tt) acc[tt] = 0.f;

    // enc part: 63 4-k quads split 16/16/16/15 across waves, 2-stage pipelined
    {
        const float* e = enc_t + row;
        const int c0 = ks * 16;
        float a0, a1, a2, a3;
        {   // prologue: load quad c0 (always < 63)
            const int j0 = c0 * 4;
            a0 = e[(j0+0)*NROWS]; a1 = e[(j0+1)*NROWS];
            a2 = e[(j0+2)*NROWS]; a3 = e[(j0+3)*NROWS];
        }
        #pragma unroll
        for (int cb = 0; cb < 16; ++cb) {
            const int ch = c0 + cb;
            float n0=0.f, n1=0.f, n2=0.f, n3=0.f;
            if (cb < 15 && ch + 1 < 63) {       // prefetch next quad
                const int jn = (ch + 1) * 4;
                n0 = e[(jn+0)*NROWS]; n1 = e[(jn+1)*NROWS];
                n2 = e[(jn+2)*NROWS]; n3 = e[(jn+3)*NROWS];
            }
            if (ch < 63) {
                const int j0 = ch * 4;
                #pragma unroll
                for (int tt = 0; tt < TT; ++tt) {
                    const float4 wv = *(const float4*)(head_w + (t0+tt)*FAN_IN + j0);
                    acc[tt] = fmaf(a0, wv.x, acc[tt]);
                    acc[tt] = fmaf(a1, wv.y, acc[tt]);
                    acc[tt] = fmaf(a2, wv.z, acc[tt]);
                    acc[tt] = fmaf(a3, wv.w, acc[tt]);
                }
            }
            a0 = n0; a1 = n1; a2 = n2; a3 = n3;
        }
    }
    // skip part: 128 4-k quads, 32 per wave, 2-stage pipelined
    {
        const float* xr = x + b * (SEQ_LEN * MM) + mh * 64 + lane;
        float a0, a1, a2, a3;
        {   // prologue
            const int l0 = (ks * 32) * 4;
            a0 = xr[(l0+0)*MM]; a1 = xr[(l0+1)*MM];
            a2 = xr[(l0+2)*MM]; a3 = xr[(l0+3)*MM];
        }
        #pragma unroll
        for (int cb = 0; cb < 32; ++cb) {
            const int l0 = (ks * 32 + cb) * 4;
            float n0=0.f, n1=0.f, n2=0.f, n3=0.f;
            if (cb < 31) {                      // prefetch next quad
                const int ln = l0 + 4;
                n0 = xr[(ln+0)*MM]; n1 = xr[(ln+1)*MM];
                n2 = xr[(ln+2)*MM]; n3 = xr[(ln+3)*MM];
            }
            #pragma unroll
            for (int tt = 0; tt < TT; ++tt) {
                const float4 wv = *(const float4*)(skip_w + (t0+tt)*SEQ_LEN + l0);
                acc[tt] = fmaf(a0, wv.x, acc[tt]);
                acc[tt] = fmaf(a1, wv.y, acc[tt]);
                acc[tt] = fmaf(a2, wv.z, acc[tt]);
                acc[tt] = fmaf(a3, wv.w, acc[tt]);
            }
            a0 = n0; a1 = n1; a2 = n2; a3 = n3;
        }
    }

    __shared__ float red[TT][256];
    #pragma unroll
    for (int tt = 0; tt < TT; ++tt) red[tt][tid] = acc[tt];
    __syncthreads();

    if (tid < 64) {
        float* o = out + b * (PRED_LEN * MM) + t0 * MM + mh * 64 + lane;
        #pragma unroll
        for (int tt = 0; tt < TT; ++tt) {
            float s = red[tt][lane] + red[tt][lane+64] + red[tt][lane+128] + red[tt][lane+192];
            o[tt * MM] = s + head_b[t0+tt] + skip_b[t0+tt];
        }
    }
}

extern "C" void kernel_launch(void* const* d_in, const int* in_sizes, int n_in,
                              void* d_out, int out_size, void* d_ws, size_t ws_size,
                              hipStream_t stream) {
    const float* x       = (const float*)d_in[0];
    const float* weights = (const float*)d_in[1];
    const float* head_w  = (const float*)d_in[2];
    const float* head_b  = (const float*)d_in[3];
    const float* skip_w  = (const float*)d_in[4];
    const float* skip_b  = (const float*)d_in[5];
    float* out = (float*)d_out;

    float* u     = (float*)d_ws;              // 512 floats
    float* enc_t = (float*)d_ws + 1024;       // 252*4096 floats = 4.13 MB

    hipLaunchKernelGGL(build_u_kernel, dim3(1), dim3(128), 0, stream, weights, u);
    hipLaunchKernelGGL(encode_kernel, dim3(63*16), dim3(256), 0, stream,
                       x, u, enc_t);
    hipLaunchKernelGGL(head_kernel, dim3(1024), dim3(256), 0, stream,
                       x, enc_t, head_w, head_b, skip_w, skip_b, out);
}